// Round 1
// baseline (165.801 us; speedup 1.0000x reference)
//
#include <hip/hip_runtime.h>
#include <math.h>

// Problem constants (from reference)
#define B 4
#define H 2
#define L 2048
#define DM 32          // d_model
#define F 16           // feat dim
#define HD 16          // head dim
#define DD 273         // 1 + F + F*F taylor feature dim
#define CHK 128        // chunk length
#define NC (L / CHK)   // 16 chunks
#define BH (B * H)     // 8

#define SC_LIN 0.5f                   // 1/RRD, RRD=2
#define SC_QUAD 0.17677669529663687f  // 1/(RD*sqrt(2)) = 1/(4*sqrt(2))

// ---------------------------------------------------------------------------
// Kernel A: fused QKV projection. q/k/v stored as (b,h,l,f) fp32.
// One block per (b,l) row; 96 of 128 threads each compute one output channel.
// ---------------------------------------------------------------------------
__global__ __launch_bounds__(128) void proj_kernel(
    const float* __restrict__ hs,
    const float* __restrict__ Wq, const float* __restrict__ Wk,
    const float* __restrict__ Wv,
    float* __restrict__ qp, float* __restrict__ kp, float* __restrict__ vp) {
  int row = blockIdx.x;  // b*L + l
  int b = row / L, l = row % L;
  __shared__ float x[DM];
  if (threadIdx.x < DM) x[threadIdx.x] = hs[(size_t)row * DM + threadIdx.x];
  __syncthreads();
  int t = threadIdx.x;
  if (t < 96) {
    int p = t / 32, c = t % 32;
    const float* W = (p == 0) ? Wq : (p == 1) ? Wk : Wv;
    float acc = 0.f;
#pragma unroll
    for (int i = 0; i < DM; i++) acc += x[i] * W[c * DM + i];
    int h = c >> 4, f = c & 15;
    float* dst = (p == 0) ? qp : (p == 1) ? kp : vp;
    dst[(((size_t)(b * H + h) * L) + l) * F + f] = acc;
  }
}

// ---------------------------------------------------------------------------
// Kernel B: per-chunk state sums.  For each (b,h,chunk):
//   S_kv[dd][hd] = sum_{s in chunk} phi(k_s)[dd] * v_s[hd]
//   S_k[dd]      = sum_{s in chunk} phi(k_s)[dd]
// phi via the padded-column trick: ks[p][16] = 1, so every dd is
// kf = sc * ks[p][i] * ks[p][j] with per-thread constant (i,j,sc).
// ---------------------------------------------------------------------------
__global__ __launch_bounds__(256) void chunksum_kernel(
    const float* __restrict__ kp, const float* __restrict__ vp,
    float* __restrict__ S_kv, float* __restrict__ S_k) {
  int blk = blockIdx.x;  // bh*NC + ch
  int bh = blk / NC, ch = blk % NC;
  __shared__ float ks[CHK][F + 1];
  __shared__ float vs[CHK][HD];
  const float* kb = kp + ((size_t)bh * L + (size_t)ch * CHK) * F;
  const float* vb = vp + ((size_t)bh * L + (size_t)ch * CHK) * F;
  for (int i = threadIdx.x; i < CHK * F; i += 256) {
    ks[i >> 4][i & 15] = kb[i];
    vs[i >> 4][i & 15] = vb[i];
  }
  for (int p = threadIdx.x; p < CHK; p += 256) ks[p][16] = 1.0f;
  __syncthreads();

  for (int rep = 0; rep < 2; rep++) {
    int dd = threadIdx.x + rep * 256;
    if (dd >= DD) break;
    int i, j;
    float sc;
    if (dd == 0) {
      i = 16; j = 16; sc = 1.0f;
    } else if (dd <= F) {
      i = dd - 1; j = 16; sc = SC_LIN;
    } else {
      int m = dd - 17;
      i = m >> 4; j = m & 15; sc = SC_QUAD;
    }
    float acc[HD];
#pragma unroll
    for (int hh = 0; hh < HD; hh++) acc[hh] = 0.f;
    float acck = 0.f;
    for (int p = 0; p < CHK; p++) {
      float kf = sc * ks[p][i] * ks[p][j];
      acck += kf;
#pragma unroll
      for (int hh = 0; hh < HD; hh++) acc[hh] += kf * vs[p][hh];
    }
    float* dst = S_kv + ((size_t)blk * DD + dd) * HD;
#pragma unroll
    for (int hh = 0; hh < HD; hh++) dst[hh] = acc[hh];
    S_k[(size_t)blk * DD + dd] = acck;
  }
}

// ---------------------------------------------------------------------------
// Kernel C: in-place exclusive prefix over the NC chunks per (b,h).
// ---------------------------------------------------------------------------
__global__ __launch_bounds__(256) void prefix_kernel(float* __restrict__ S_kv,
                                                     float* __restrict__ S_k) {
  int bh = blockIdx.x;
  for (int e = threadIdx.x; e < DD * HD; e += 256) {
    float run = 0.f;
    for (int c = 0; c < NC; c++) {
      size_t idx = ((size_t)(bh * NC + c)) * (DD * HD) + e;
      float v = S_kv[idx];
      S_kv[idx] = run;
      run += v;
    }
  }
  for (int e = threadIdx.x; e < DD; e += 256) {
    float run = 0.f;
    for (int c = 0; c < NC; c++) {
      size_t idx = ((size_t)(bh * NC + c)) * DD + e;
      float v = S_k[idx];
      S_k[idx] = run;
      run += v;
    }
  }
}

// ---------------------------------------------------------------------------
// Kernel D: per-chunk output.  One thread per position t.
//   inter: phi(q_t) . S (exclusive prefix state, LDS-resident)
//   intra: closed-form score(q_t,k_s) = 1 + dot/4 + dot^2/32, s<=t in chunk
// y stored (b, l, h*HD+hd) so the Wo projection reads contiguously.
// ---------------------------------------------------------------------------
__global__ __launch_bounds__(128) void outchunk_kernel(
    const float* __restrict__ qp, const float* __restrict__ kp,
    const float* __restrict__ vp, const float* __restrict__ St_kv,
    const float* __restrict__ St_k, float* __restrict__ y) {
  int blk = blockIdx.x;  // bh*NC + ch
  int bh = blk / NC, ch = blk % NC;
  int b = bh / H, h = bh % H;
  __shared__ float qs[CHK][F + 1];
  __shared__ float ks[CHK][F + 1];
  __shared__ float vs[CHK][HD];
  __shared__ float S[DD * HD];
  __shared__ float Sk[DD];

  const float* qb = qp + ((size_t)bh * L + (size_t)ch * CHK) * F;
  const float* kb = kp + ((size_t)bh * L + (size_t)ch * CHK) * F;
  const float* vb = vp + ((size_t)bh * L + (size_t)ch * CHK) * F;
  for (int i = threadIdx.x; i < CHK * F; i += 128) {
    int p = i >> 4, f = i & 15;
    qs[p][f] = qb[i];
    ks[p][f] = kb[i];
    vs[p][f] = vb[i];
  }
  for (int p = threadIdx.x; p < CHK; p += 128) {
    qs[p][16] = 1.0f;
    ks[p][16] = 1.0f;
  }
  const float* Sb = St_kv + (size_t)blk * DD * HD;
  for (int i = threadIdx.x; i < DD * HD; i += 128) S[i] = Sb[i];
  const float* Skb = St_k + (size_t)blk * DD;
  for (int i = threadIdx.x; i < DD; i += 128) Sk[i] = Skb[i];
  __syncthreads();

  int t = threadIdx.x;  // position in chunk
  float qreg[F];
#pragma unroll
  for (int i = 0; i < F; i++) qreg[i] = qs[t][i];

  float acc[HD];
#pragma unroll
  for (int hh = 0; hh < HD; hh++) acc[hh] = 0.f;
  float den = 0.f;

  // ---- inter: dd = 0 (constant feature)
  den += Sk[0];
#pragma unroll
  for (int hh = 0; hh < HD; hh++) acc[hh] += S[hh];

  // ---- inter: linear features
  for (int i = 0; i < F; i++) {
    float qf = qs[t][i] * SC_LIN;  // dynamic i -> LDS read (2-way, free)
    den += qf * Sk[1 + i];
    const float* Srow = &S[(1 + i) * HD];
#pragma unroll
    for (int hh = 0; hh < HD; hh++) acc[hh] += qf * Srow[hh];
  }

  // ---- inter: quadratic features
  for (int i = 0; i < F; i++) {
    float qi = qs[t][i] * SC_QUAD;
    const float* Srow = &S[(17 + i * 16) * HD];
    const float* Skrow = &Sk[17 + i * 16];
#pragma unroll
    for (int j = 0; j < F; j++) {
      float qf = qi * qreg[j];
      den += qf * Skrow[j];
#pragma unroll
      for (int hh = 0; hh < HD; hh++) acc[hh] += qf * Srow[j * HD + hh];
    }
  }

  // ---- intra-chunk causal part via closed-form feature dot
  for (int s = 0; s < CHK; s++) {
    if (s > t) break;
    float dot = 0.f;
#pragma unroll
    for (int i = 0; i < F; i++) dot += qreg[i] * ks[s][i];
    float scv = 1.0f + dot * 0.25f + dot * dot * 0.03125f;
    den += scv;
#pragma unroll
    for (int hh = 0; hh < HD; hh++) acc[hh] += scv * vs[s][hh];
  }

  float inv = 1.0f / (den + 1e-12f);
  float* yb = y + (((size_t)(b * L + ch * CHK + t)) * H + h) * HD;
#pragma unroll
  for (int hh = 0; hh < HD; hh++) yb[hh] = acc[hh] * inv;
}

// ---------------------------------------------------------------------------
// Kernel E: output projection out = y @ Wo^T, one thread per (b,l,oc).
// ---------------------------------------------------------------------------
__global__ __launch_bounds__(256) void out_kernel(const float* __restrict__ y,
                                                  const float* __restrict__ Wo,
                                                  float* __restrict__ out) {
  int idx = blockIdx.x * 256 + threadIdx.x;
  if (idx >= B * L * DM) return;
  int row = idx >> 5, oc = idx & 31;
  const float* yr = y + (size_t)row * 32;
  const float* wr = Wo + oc * 32;
  float acc = 0.f;
#pragma unroll
  for (int c = 0; c < 32; c++) acc += yr[c] * wr[c];
  out[idx] = acc;
}

extern "C" void kernel_launch(void* const* d_in, const int* in_sizes, int n_in,
                              void* d_out, int out_size, void* d_ws,
                              size_t ws_size, hipStream_t stream) {
  const float* hs = (const float*)d_in[0];
  const float* Wq = (const float*)d_in[1];
  const float* Wk = (const float*)d_in[2];
  const float* Wv = (const float*)d_in[3];
  const float* Wo = (const float*)d_in[4];
  float* out = (float*)d_out;

  float* ws = (float*)d_ws;
  float* qp = ws;                          // BH*L*F
  float* kp = qp + (size_t)BH * L * F;     // BH*L*F
  float* vp = kp + (size_t)BH * L * F;     // BH*L*F
  float* S_kv = vp + (size_t)BH * L * F;   // BH*NC*DD*HD
  float* S_k = S_kv + (size_t)BH * NC * DD * HD;  // BH*NC*DD
  float* y = S_k + (size_t)BH * NC * DD;   // B*L*H*HD
  // total ~6.6 MB of fp32 workspace

  proj_kernel<<<B * L, 128, 0, stream>>>(hs, Wq, Wk, Wv, qp, kp, vp);
  chunksum_kernel<<<BH * NC, 256, 0, stream>>>(kp, vp, S_kv, S_k);
  prefix_kernel<<<BH, 256, 0, stream>>>(S_kv, S_k);
  outchunk_kernel<<<BH * NC, 128, 0, stream>>>(qp, kp, vp, S_kv, S_k, y);
  out_kernel<<<(B * L * DM + 255) / 256, 256, 0, stream>>>(y, Wo, out);
}